// Round 3
// baseline (482.695 us; speedup 1.0000x reference)
//
#include <hip/hip_runtime.h>

// Batched 10-qubit statevector simulator — one 64-lane wave per sample.
// State: 1024 complex amps; s = (r<<6)|lane; qubit q <-> bit (9-q):
//   qubits 0..3 -> register-index bits (16 complex per lane = 32 VGPR)
//   qubits 4..9 -> lane bits (shfl_xor butterflies)
// Per layer per qubit, RY(a)RZ(b)RZ(g)RY(d) fuse into one SU(2)
// U = [[u, -conj(v)],[v, conj(u)]], p=(b+g)/2:
//   u = (cd*ca - sd*sa)*cp - i*(cd*ca + sd*sa)*sp
//   v = (cd*sa + sd*ca)*cp + i*(cd*sa - sd*ca)*sp
// R1: all 50 gate coefficient sets computed in PARALLEL across lanes
// (lane g = layer*10+q computes gate g), broadcast at use via v_readlane
// into SGPRs. R2 FIX: readlane is int-typed — must BIT-CAST floats through
// it (__float_as_int / __int_as_float), not pass them directly (implicit
// numeric conversion truncated all coefficients — absmax 0.18 in R1).

constexpr int NQ  = 10;
constexpr int NL  = 5;
constexpr int OBS = 10;

__device__ __forceinline__ float readlane_f(float v, int l) {
    return __int_as_float(__builtin_amdgcn_readlane(__float_as_int(v), l));
}

__global__ __launch_bounds__(256, 8) void qsim_kernel(
    const float* __restrict__ x,       // (B, 10)
    const float* __restrict__ isc,     // (5, 20)
    const float* __restrict__ w,       // (5, 20)
    const float* __restrict__ oscale,  // (4)
    float* __restrict__ out,           // (B, 4)
    int B)
{
    const int lane = threadIdx.x & 63;
    const int wid  = (blockIdx.x * blockDim.x + threadIdx.x) >> 6;
    if (wid >= B) return;

    // ---- lane-parallel gate-coefficient computation (gates 0..49) ----
    // lane g (clamped to 49) handles layer=g/10, qubit=g%10.
    float cUR, cUI, cVR, cVI;
    {
        const int g   = (lane < 50) ? lane : 49;
        const int q   = g % 10;
        const int lyr = g / 10;
        const float xq    = x[wid * OBS + q];
        const float alpha = isc[lyr * 2 * NQ + q]      * xq;
        const float beta  = isc[lyr * 2 * NQ + NQ + q] * xq;
        const float gamma = w[lyr * 2 * NQ + q];
        const float delta = w[lyr * 2 * NQ + NQ + q];
        float sa, ca, sp, cp, sd, cd;
        __sincosf(0.5f * alpha,          &sa, &ca);
        __sincosf(0.5f * (beta + gamma), &sp, &cp);
        __sincosf(0.5f * delta,          &sd, &cd);
        const float A = cd * ca, Bt = sd * sa;
        const float C = cd * sa, D  = sd * ca;
        cUR = (A - Bt) * cp;
        cUI = -(A + Bt) * sp;
        cVR = (C + D) * cp;
        cVI = (C - D) * sp;
    }

    float ar[16], ai[16];
#pragma unroll
    for (int r = 0; r < 16; ++r) { ar[r] = 0.f; ai[r] = 0.f; }
    ar[0] = (lane == 0) ? 1.f : 0.f;   // |0...0>

#define SWAPR(i, j) { float _tr = ar[i], _ti = ai[i]; \
                      ar[i] = ar[j]; ai[i] = ai[j];   \
                      ar[j] = _tr;  ai[j] = _ti; }

    for (int layer = 0; layer < NL; ++layer) {
        const int base = layer * NQ;   // wave-uniform

        // ---- fused single-qubit unitaries, one per qubit ----
#pragma unroll
        for (int q = 0; q < NQ; ++q) {
            // broadcast gate coefficients from lane base+q into SGPRs
            const float ur = readlane_f(cUR, base + q);
            const float ui = readlane_f(cUI, base + q);
            const float vr = readlane_f(cVR, base + q);
            const float vi = readlane_f(cVI, base + q);

            if (q < 4) {
                // register-bit qubit: pair stride m inside the lane
                const int m = 1 << (3 - q);
#pragma unroll
                for (int r0 = 0; r0 < 16; ++r0) {
                    if (r0 & m) continue;
                    const int r1 = r0 | m;
                    const float s0r = ar[r0], s0i = ai[r0];
                    const float s1r = ar[r1], s1i = ai[r1];
                    // new0 = u*s0 - conj(v)*s1 ; new1 = v*s0 + conj(u)*s1
                    ar[r0] = ur*s0r - ui*s0i - vr*s1r - vi*s1i;
                    ai[r0] = ur*s0i + ui*s0r - vr*s1i + vi*s1r;
                    ar[r1] = vr*s0r - vi*s0i + ur*s1r + ui*s1i;
                    ai[r1] = vr*s0i + vi*s0r + ur*s1i - ui*s1r;
                }
            } else {
                // lane-bit qubit: butterfly exchange with lane^M
                const int  M   = 1 << (9 - q);
                const bool bit = (lane & M) != 0;
                //  bit0: new = u*mine - conj(v)*partner
                //  bit1: new = conj(u)*mine + v*partner
                const float Pi = bit ? -ui : ui;     // Pr = ur always
                const float Qr = bit ?  vr : -vr;    // Qi = vi always
#pragma unroll
                for (int r = 0; r < 16; ++r) {
                    const float pr = __shfl_xor(ar[r], M, 64);
                    const float pi = __shfl_xor(ai[r], M, 64);
                    const float mr = ar[r], mi = ai[r];
                    ar[r] = ur*mr - Pi*mi + Qr*pr - vi*pi;
                    ai[r] = ur*mi + Pi*mr + Qr*pi + vi*pr;
                }
            }
        }

        // ---- CNOT ring: (0,1),(1,2),...,(8,9),(9,0), sequential ----
        // CNOT(0,1): ctrl r-bit3, tgt r-bit2 -> register swap
        SWAPR(8, 12) SWAPR(9, 13) SWAPR(10, 14) SWAPR(11, 15)
        // CNOT(1,2): ctrl r-bit2, tgt r-bit1
        SWAPR(4, 6)  SWAPR(5, 7)  SWAPR(12, 14) SWAPR(13, 15)
        // CNOT(2,3): ctrl r-bit1, tgt r-bit0
        SWAPR(2, 3)  SWAPR(6, 7)  SWAPR(10, 11) SWAPR(14, 15)
        // CNOT(3,4): ctrl r-bit0 (r odd), tgt lane-bit5 (mask 32)
#pragma unroll
        for (int r = 1; r < 16; r += 2) {
            const float tr = __shfl_xor(ar[r], 32, 64);
            const float ti = __shfl_xor(ai[r], 32, 64);
            ar[r] = tr; ai[r] = ti;
        }
        // CNOT(q,q+1) for q=4..8: ctrl lane mask Mc, tgt mask Mc>>1
#pragma unroll
        for (int q = 4; q <= 8; ++q) {
            const int  Mc  = 1 << (9 - q);
            const int  Mt  = Mc >> 1;
            const bool ctl = (lane & Mc) != 0;
#pragma unroll
            for (int r = 0; r < 16; ++r) {
                const float tr = __shfl_xor(ar[r], Mt, 64);
                const float ti = __shfl_xor(ai[r], Mt, 64);
                if (ctl) { ar[r] = tr; ai[r] = ti; }
            }
        }
        // CNOT(9,0): ctrl lane-bit0, tgt r-bit3 -> conditional register swap
        {
            const bool ctl = (lane & 1) != 0;
#pragma unroll
            for (int r = 0; r < 8; ++r) {
                const float t0r = ar[r],     t0i = ai[r];
                const float t1r = ar[r + 8], t1i = ai[r + 8];
                ar[r]     = ctl ? t1r : t0r;
                ai[r]     = ctl ? t1i : t0i;
                ar[r + 8] = ctl ? t0r : t1r;
                ai[r + 8] = ctl ? t0i : t1i;
            }
        }
    }

    // ---- <Z_i> for qubits 0..3 (all register bits) ----
    float z0 = 0.f, z1 = 0.f, z2 = 0.f, z3 = 0.f;
#pragma unroll
    for (int r = 0; r < 16; ++r) {
        const float pv = ar[r] * ar[r] + ai[r] * ai[r];
        z0 += (r & 8) ? -pv : pv;
        z1 += (r & 4) ? -pv : pv;
        z2 += (r & 2) ? -pv : pv;
        z3 += (r & 1) ? -pv : pv;
    }
#pragma unroll
    for (int m = 1; m < 64; m <<= 1) {
        z0 += __shfl_xor(z0, m, 64);
        z1 += __shfl_xor(z1, m, 64);
        z2 += __shfl_xor(z2, m, 64);
        z3 += __shfl_xor(z3, m, 64);
    }
    if (lane == 0) {
        out[wid * 4 + 0] = z0 * oscale[0];
        out[wid * 4 + 1] = z1 * oscale[1];
        out[wid * 4 + 2] = z2 * oscale[2];
        out[wid * 4 + 3] = z3 * oscale[3];
    }
#undef SWAPR
}

extern "C" void kernel_launch(void* const* d_in, const int* in_sizes, int n_in,
                              void* d_out, int out_size, void* d_ws, size_t ws_size,
                              hipStream_t stream) {
    const float* x      = (const float*)d_in[0];
    const float* isc    = (const float*)d_in[1];
    const float* w      = (const float*)d_in[2];
    const float* oscale = (const float*)d_in[3];
    float* out = (float*)d_out;

    const int B = in_sizes[0] / OBS;             // 4096
    const int threads = 256;                     // 4 waves -> 4 samples per block
    const int blocks = (B * 64 + threads - 1) / threads;
    qsim_kernel<<<blocks, threads, 0, stream>>>(x, isc, w, oscale, out, B);
}

// Round 4
// 122.538 us; speedup vs baseline: 3.9392x; 3.9392x over previous
//
#include <hip/hip_runtime.h>

// Batched 10-qubit statevector simulator — one 64-lane wave per sample.
// State: 1024 complex amps; s = (r<<6)|lane; qubit q <-> bit (9-q):
//   qubits 0..3 -> register-index bits (16 complex per lane = 32 VGPR)
//   qubits 4..9 -> lane bits (shfl_xor butterflies)
// Per layer per qubit, RY(a)RZ(b)RZ(g)RY(d) fuse into one SU(2)
// U = [[u, -conj(v)],[v, conj(u)]], p=(b+g)/2.
// R1/R2: 50 gate coefficient sets computed lane-parallel (lane g=layer*10+q),
// broadcast via v_readlane (BIT-CAST through int — readlane is int-typed).
// R3: (a) __launch_bounds__(256,4): grid is exactly 4 waves/SIMD, so cap
//     VGPR at 128 — R2's (256,8) forced 64-VGPR budget and spilled the whole
//     state to scratch (2.1 GB HBM traffic, 3.5x slower).
//     (b) CNOT chain (3,4)(4,5)...(8,9) fused into ONE ds_bpermute pass:
//     composed affine lane permutation, dest lane d pulls from
//     s = (d ^ (d>>1)) ^ ((r&1)<<5). Replaces 168 cond-shuffles + 160
//     cndmask per layer with 32 unconditional bpermutes.

constexpr int NQ  = 10;
constexpr int NL  = 5;
constexpr int OBS = 10;

__device__ __forceinline__ float readlane_f(float v, int l) {
    return __int_as_float(__builtin_amdgcn_readlane(__float_as_int(v), l));
}
__device__ __forceinline__ float bperm_f(int byte_addr, float v) {
    return __int_as_float(__builtin_amdgcn_ds_bpermute(byte_addr, __float_as_int(v)));
}

__global__ __launch_bounds__(256, 4) void qsim_kernel(
    const float* __restrict__ x,       // (B, 10)
    const float* __restrict__ isc,     // (5, 20)
    const float* __restrict__ w,       // (5, 20)
    const float* __restrict__ oscale,  // (4)
    float* __restrict__ out,           // (B, 4)
    int B)
{
    const int lane = threadIdx.x & 63;
    const int wid  = (blockIdx.x * blockDim.x + threadIdx.x) >> 6;
    if (wid >= B) return;

    // ---- lane-parallel gate-coefficient computation (gates 0..49) ----
    float cUR, cUI, cVR, cVI;
    {
        const int g   = (lane < 50) ? lane : 49;
        const int q   = g % 10;
        const int lyr = g / 10;
        const float xq    = x[wid * OBS + q];
        const float alpha = isc[lyr * 2 * NQ + q]      * xq;
        const float beta  = isc[lyr * 2 * NQ + NQ + q] * xq;
        const float gamma = w[lyr * 2 * NQ + q];
        const float delta = w[lyr * 2 * NQ + NQ + q];
        float sa, ca, sp, cp, sd, cd;
        __sincosf(0.5f * alpha,          &sa, &ca);
        __sincosf(0.5f * (beta + gamma), &sp, &cp);
        __sincosf(0.5f * delta,          &sd, &cd);
        const float A = cd * ca, Bt = sd * sa;
        const float C = cd * sa, D  = sd * ca;
        cUR = (A - Bt) * cp;
        cUI = -(A + Bt) * sp;
        cVR = (C + D) * cp;
        cVI = (C - D) * sp;
    }

    // fused-CNOT bpermute source addresses (loop-invariant)
    const int cnot_src   = (lane ^ (lane >> 1));        // lane-bit chain pull src
    const int addr_even  = cnot_src * 4;                // r bit0 == 0
    const int addr_odd   = (cnot_src ^ 32) * 4;         // r bit0 == 1 (CNOT(3,4))

    float ar[16], ai[16];
#pragma unroll
    for (int r = 0; r < 16; ++r) { ar[r] = 0.f; ai[r] = 0.f; }
    ar[0] = (lane == 0) ? 1.f : 0.f;   // |0...0>

#define SWAPR(i, j) { float _tr = ar[i], _ti = ai[i]; \
                      ar[i] = ar[j]; ai[i] = ai[j];   \
                      ar[j] = _tr;  ai[j] = _ti; }

    for (int layer = 0; layer < NL; ++layer) {
        const int base = layer * NQ;   // wave-uniform

        // ---- fused single-qubit unitaries, one per qubit ----
#pragma unroll
        for (int q = 0; q < NQ; ++q) {
            const float ur = readlane_f(cUR, base + q);
            const float ui = readlane_f(cUI, base + q);
            const float vr = readlane_f(cVR, base + q);
            const float vi = readlane_f(cVI, base + q);

            if (q < 4) {
                // register-bit qubit: pair stride m inside the lane
                const int m = 1 << (3 - q);
#pragma unroll
                for (int r0 = 0; r0 < 16; ++r0) {
                    if (r0 & m) continue;
                    const int r1 = r0 | m;
                    const float s0r = ar[r0], s0i = ai[r0];
                    const float s1r = ar[r1], s1i = ai[r1];
                    // new0 = u*s0 - conj(v)*s1 ; new1 = v*s0 + conj(u)*s1
                    ar[r0] = ur*s0r - ui*s0i - vr*s1r - vi*s1i;
                    ai[r0] = ur*s0i + ui*s0r - vr*s1i + vi*s1r;
                    ar[r1] = vr*s0r - vi*s0i + ur*s1r + ui*s1i;
                    ai[r1] = vr*s0i + vi*s0r + ur*s1i - ui*s1r;
                }
            } else {
                // lane-bit qubit: butterfly exchange with lane^M
                const int  M   = 1 << (9 - q);
                const bool bit = (lane & M) != 0;
                const float Pi = bit ? -ui : ui;     // Pr = ur always
                const float Qr = bit ?  vr : -vr;    // Qi = vi always
#pragma unroll
                for (int r = 0; r < 16; ++r) {
                    const float pr = __shfl_xor(ar[r], M, 64);
                    const float pi = __shfl_xor(ai[r], M, 64);
                    const float mr = ar[r], mi = ai[r];
                    ar[r] = ur*mr - Pi*mi + Qr*pr - vi*pi;
                    ai[r] = ur*mi + Pi*mr + Qr*pi + vi*pr;
                }
            }
        }

        // ---- CNOT ring: (0,1),(1,2),...,(8,9),(9,0), sequential ----
        // CNOT(0,1): ctrl r-bit3, tgt r-bit2 -> register swap
        SWAPR(8, 12) SWAPR(9, 13) SWAPR(10, 14) SWAPR(11, 15)
        // CNOT(1,2): ctrl r-bit2, tgt r-bit1
        SWAPR(4, 6)  SWAPR(5, 7)  SWAPR(12, 14) SWAPR(13, 15)
        // CNOT(2,3): ctrl r-bit1, tgt r-bit0
        SWAPR(2, 3)  SWAPR(6, 7)  SWAPR(10, 11) SWAPR(14, 15)
        // CNOT(3,4)..(8,9) fused: one bpermute per register value.
#pragma unroll
        for (int r = 0; r < 16; ++r) {
            const int addr = (r & 1) ? addr_odd : addr_even;
            ar[r] = bperm_f(addr, ar[r]);
            ai[r] = bperm_f(addr, ai[r]);
        }
        // CNOT(9,0): ctrl lane-bit0, tgt r-bit3 -> conditional register swap
        {
            const bool ctl = (lane & 1) != 0;
#pragma unroll
            for (int r = 0; r < 8; ++r) {
                const float t0r = ar[r],     t0i = ai[r];
                const float t1r = ar[r + 8], t1i = ai[r + 8];
                ar[r]     = ctl ? t1r : t0r;
                ai[r]     = ctl ? t1i : t0i;
                ar[r + 8] = ctl ? t0r : t1r;
                ai[r + 8] = ctl ? t0i : t1i;
            }
        }
    }

    // ---- <Z_i> for qubits 0..3 (all register bits) ----
    float z0 = 0.f, z1 = 0.f, z2 = 0.f, z3 = 0.f;
#pragma unroll
    for (int r = 0; r < 16; ++r) {
        const float pv = ar[r] * ar[r] + ai[r] * ai[r];
        z0 += (r & 8) ? -pv : pv;
        z1 += (r & 4) ? -pv : pv;
        z2 += (r & 2) ? -pv : pv;
        z3 += (r & 1) ? -pv : pv;
    }
#pragma unroll
    for (int m = 1; m < 64; m <<= 1) {
        z0 += __shfl_xor(z0, m, 64);
        z1 += __shfl_xor(z1, m, 64);
        z2 += __shfl_xor(z2, m, 64);
        z3 += __shfl_xor(z3, m, 64);
    }
    if (lane == 0) {
        out[wid * 4 + 0] = z0 * oscale[0];
        out[wid * 4 + 1] = z1 * oscale[1];
        out[wid * 4 + 2] = z2 * oscale[2];
        out[wid * 4 + 3] = z3 * oscale[3];
    }
#undef SWAPR
}

extern "C" void kernel_launch(void* const* d_in, const int* in_sizes, int n_in,
                              void* d_out, int out_size, void* d_ws, size_t ws_size,
                              hipStream_t stream) {
    const float* x      = (const float*)d_in[0];
    const float* isc    = (const float*)d_in[1];
    const float* w      = (const float*)d_in[2];
    const float* oscale = (const float*)d_in[3];
    float* out = (float*)d_out;

    const int B = in_sizes[0] / OBS;             // 4096
    const int threads = 256;                     // 4 waves -> 4 samples per block
    const int blocks = (B * 64 + threads - 1) / threads;
    qsim_kernel<<<blocks, threads, 0, stream>>>(x, isc, w, oscale, out, B);
}

// Round 5
// 113.258 us; speedup vs baseline: 4.2619x; 1.0819x over previous
//
#include <hip/hip_runtime.h>

// Batched 10-qubit statevector simulator — one 64-lane wave per sample.
// State: 1024 complex amps; s = (r<<6)|lane; qubit q <-> bit (9-q):
//   qubits 0..3 -> register-index bits (16 complex per lane, stored as
//                  float2 (re,im) -> 32 VGPRs)
//   qubits 4..9 -> lane bits (shfl_xor butterflies)
// Per layer per qubit, RY(a)RZ(b)RZ(g)RY(d) fuse into one SU(2)
// U = [[u, -conj(v)],[v, conj(u)]], p=(b+g)/2.
// R1/R2: 50 gate coefficient sets computed lane-parallel (lane g=layer*10+q),
//        broadcast via v_readlane (bit-cast through int).
// R3: __launch_bounds__(256,4) (grid = exactly 4 waves/SIMD; (256,8) spilled
//     the state -> 2.1 GB scratch traffic). CNOT chain (3,4)..(8,9) fused to
//     one ds_bpermute pass: dest lane d pulls s = (d ^ (d>>1)) ^ ((r&1)<<5).
// R4: complex packed as float2 ext-vector; gate updates written as <2 x float>
//     mul/fma so the backend emits VOP3P v_pk_fma_f32 (2 f32/inst) — halves
//     VALU issue for the ~6400 gate FMAs. Sign-asymmetric packed coefficients
//     ((-ui,ui) etc.) built once per gate; re<->im swap via .yx swizzle
//     (folds to op_sel).

constexpr int NQ  = 10;
constexpr int NL  = 5;
constexpr int OBS = 10;

typedef float f2 __attribute__((ext_vector_type(2)));

__device__ __forceinline__ float readlane_f(float v, int l) {
    return __int_as_float(__builtin_amdgcn_readlane(__float_as_int(v), l));
}
__device__ __forceinline__ float bperm_f(int byte_addr, float v) {
    return __int_as_float(__builtin_amdgcn_ds_bpermute(byte_addr, __float_as_int(v)));
}

__global__ __launch_bounds__(256, 4) void qsim_kernel(
    const float* __restrict__ x,       // (B, 10)
    const float* __restrict__ isc,     // (5, 20)
    const float* __restrict__ w,       // (5, 20)
    const float* __restrict__ oscale,  // (4)
    float* __restrict__ out,           // (B, 4)
    int B)
{
    const int lane = threadIdx.x & 63;
    const int wid  = (blockIdx.x * blockDim.x + threadIdx.x) >> 6;
    if (wid >= B) return;

    // ---- lane-parallel gate-coefficient computation (gates 0..49) ----
    float cUR, cUI, cVR, cVI;
    {
        const int g   = (lane < 50) ? lane : 49;
        const int q   = g % 10;
        const int lyr = g / 10;
        const float xq    = x[wid * OBS + q];
        const float alpha = isc[lyr * 2 * NQ + q]      * xq;
        const float beta  = isc[lyr * 2 * NQ + NQ + q] * xq;
        const float gamma = w[lyr * 2 * NQ + q];
        const float delta = w[lyr * 2 * NQ + NQ + q];
        float sa, ca, sp, cp, sd, cd;
        __sincosf(0.5f * alpha,          &sa, &ca);
        __sincosf(0.5f * (beta + gamma), &sp, &cp);
        __sincosf(0.5f * delta,          &sd, &cd);
        const float A = cd * ca, Bt = sd * sa;
        const float C = cd * sa, D  = sd * ca;
        cUR = (A - Bt) * cp;
        cUI = -(A + Bt) * sp;
        cVR = (C + D) * cp;
        cVI = (C - D) * sp;
    }

    // fused-CNOT bpermute source addresses (loop-invariant)
    const int cnot_src  = (lane ^ (lane >> 1));
    const int addr_even = cnot_src * 4;            // r bit0 == 0
    const int addr_odd  = (cnot_src ^ 32) * 4;     // r bit0 == 1 (CNOT(3,4))

    f2 c[16];
#pragma unroll
    for (int r = 0; r < 16; ++r) c[r] = (f2){0.f, 0.f};
    c[0].x = (lane == 0) ? 1.f : 0.f;   // |0...0>

#define SWAPR(i, j) { f2 _t = c[i]; c[i] = c[j]; c[j] = _t; }

    for (int layer = 0; layer < NL; ++layer) {
        const int base = layer * NQ;   // wave-uniform

        // ---- fused single-qubit unitaries, one per qubit ----
#pragma unroll
        for (int q = 0; q < NQ; ++q) {
            const float ur = readlane_f(cUR, base + q);
            const float ui = readlane_f(cUI, base + q);
            const float vr = readlane_f(cVR, base + q);
            const float vi = readlane_f(cVI, base + q);

            if (q < 4) {
                // register-bit qubit: pair stride m inside the lane.
                // c0' = (ur,ur)c0 + (-ui,ui)c0s + (-vr,-vr)c1 + (-vi,vi)c1s
                // c1' = (vr,vr)c0 + (-vi,vi)c0s + ( ur,ur)c1 + (ui,-ui)c1s
                const f2 kUU  = {ur, ur};
                const f2 kUIm = {-ui, ui};
                const f2 kVVn = {-vr, -vr};
                const f2 kVV  = {vr, vr};
                const f2 kVIm = {-vi, vi};
                const f2 kUIp = {ui, -ui};
                const int m = 1 << (3 - q);
#pragma unroll
                for (int r0 = 0; r0 < 16; ++r0) {
                    if (r0 & m) continue;
                    const int r1 = r0 | m;
                    const f2 c0 = c[r0], c1 = c[r1];
                    const f2 c0s = c0.yx, c1s = c1.yx;
                    c[r0] = kUU*c0 + kUIm*c0s + kVVn*c1 + kVIm*c1s;
                    c[r1] = kVV*c0 + kVIm*c0s + kUU*c1  + kUIp*c1s;
                }
            } else {
                // lane-bit qubit: butterfly exchange with lane^M.
                // new = (ur,ur)m + (-Pi,Pi)ms + (Qr,Qr)p + (-vi,vi)ps
                const int  M   = 1 << (9 - q);
                const bool bit = (lane & M) != 0;
                const float Pi = bit ? -ui : ui;
                const float Qr = bit ?  vr : -vr;
                const f2 kUU = {ur, ur};
                const f2 kPI = {-Pi, Pi};
                const f2 kQR = {Qr, Qr};
                const f2 kVI = {-vi, vi};
#pragma unroll
                for (int r = 0; r < 16; ++r) {
                    const f2 mv = c[r];
                    f2 pv;
                    pv.x = __shfl_xor(mv.x, M, 64);
                    pv.y = __shfl_xor(mv.y, M, 64);
                    c[r] = kUU*mv + kPI*mv.yx + kQR*pv + kVI*pv.yx;
                }
            }
        }

        // ---- CNOT ring: (0,1),(1,2),...,(8,9),(9,0), sequential ----
        // CNOT(0,1): ctrl r-bit3, tgt r-bit2 -> register swap
        SWAPR(8, 12) SWAPR(9, 13) SWAPR(10, 14) SWAPR(11, 15)
        // CNOT(1,2): ctrl r-bit2, tgt r-bit1
        SWAPR(4, 6)  SWAPR(5, 7)  SWAPR(12, 14) SWAPR(13, 15)
        // CNOT(2,3): ctrl r-bit1, tgt r-bit0
        SWAPR(2, 3)  SWAPR(6, 7)  SWAPR(10, 11) SWAPR(14, 15)
        // CNOT(3,4)..(8,9) fused: one bpermute per 32-bit value.
#pragma unroll
        for (int r = 0; r < 16; ++r) {
            const int addr = (r & 1) ? addr_odd : addr_even;
            c[r].x = bperm_f(addr, c[r].x);
            c[r].y = bperm_f(addr, c[r].y);
        }
        // CNOT(9,0): ctrl lane-bit0, tgt r-bit3 -> conditional register swap
        {
            const bool ctl = (lane & 1) != 0;
#pragma unroll
            for (int r = 0; r < 8; ++r) {
                const f2 t0 = c[r], t1 = c[r + 8];
                c[r]     = ctl ? t1 : t0;
                c[r + 8] = ctl ? t0 : t1;
            }
        }
    }

    // ---- <Z_i> for qubits 0..3 (all register bits) ----
    float z0 = 0.f, z1 = 0.f, z2 = 0.f, z3 = 0.f;
#pragma unroll
    for (int r = 0; r < 16; ++r) {
        const float pv = c[r].x * c[r].x + c[r].y * c[r].y;
        z0 += (r & 8) ? -pv : pv;
        z1 += (r & 4) ? -pv : pv;
        z2 += (r & 2) ? -pv : pv;
        z3 += (r & 1) ? -pv : pv;
    }
#pragma unroll
    for (int m = 1; m < 64; m <<= 1) {
        z0 += __shfl_xor(z0, m, 64);
        z1 += __shfl_xor(z1, m, 64);
        z2 += __shfl_xor(z2, m, 64);
        z3 += __shfl_xor(z3, m, 64);
    }
    if (lane == 0) {
        out[wid * 4 + 0] = z0 * oscale[0];
        out[wid * 4 + 1] = z1 * oscale[1];
        out[wid * 4 + 2] = z2 * oscale[2];
        out[wid * 4 + 3] = z3 * oscale[3];
    }
#undef SWAPR
}

extern "C" void kernel_launch(void* const* d_in, const int* in_sizes, int n_in,
                              void* d_out, int out_size, void* d_ws, size_t ws_size,
                              hipStream_t stream) {
    const float* x      = (const float*)d_in[0];
    const float* isc    = (const float*)d_in[1];
    const float* w      = (const float*)d_in[2];
    const float* oscale = (const float*)d_in[3];
    float* out = (float*)d_out;

    const int B = in_sizes[0] / OBS;             // 4096
    const int threads = 256;                     // 4 waves -> 4 samples per block
    const int blocks = (B * 64 + threads - 1) / threads;
    qsim_kernel<<<blocks, threads, 0, stream>>>(x, isc, w, oscale, out, B);
}

// Round 6
// 97.320 us; speedup vs baseline: 4.9599x; 1.1638x over previous
//
#include <hip/hip_runtime.h>

// Batched 10-qubit statevector simulator — one 64-lane wave per sample.
// State: 1024 complex amps; s = (r<<6)|lane; qubit q <-> bit (9-q):
//   qubits 0..3 -> register-index bits (16 complex float2 per lane)
//   qubits 4..9 -> lane bits (butterfly exchanges)
// Per layer per qubit, RY(a)RZ(b)RZ(g)RY(d) fuse into one SU(2)
// U = [[u, -conj(v)],[v, conj(u)]], p=(b+g)/2.
// R1/R2: 50 gate coefficient sets computed lane-parallel, broadcast via
//        v_readlane (bit-cast through int).
// R3: __launch_bounds__(256,4) (grid = exactly 4 waves/SIMD; (256,8) spilled).
//     CNOT chain (3,4)..(8,9) fused to one ds_bpermute pass:
//     dest lane d pulls s = (d ^ (d>>1)) ^ ((r&1)<<5).
// R4: float2 ext-vector state -> VOP3P v_pk_fma_f32 (2 f32/inst).
// R5: DS-pipe relief — xor-masks 1,2 (quad_perm DPP) and 8 (row_ror:8 DPP)
//     become v_mov_b32_dpp on the VALU pipe (free vs ~6cyc DS); masks
//     4/16/32 use ds_bpermute with hoisted addresses. DS ops/wave
//     ~1140 -> ~670 (VALUBusy was 41% — headroom for the movs).

constexpr int NQ  = 10;
constexpr int NL  = 5;
constexpr int OBS = 10;

typedef float f2 __attribute__((ext_vector_type(2)));

__device__ __forceinline__ float readlane_f(float v, int l) {
    return __int_as_float(__builtin_amdgcn_readlane(__float_as_int(v), l));
}
__device__ __forceinline__ float bperm_f(int byte_addr, float v) {
    return __int_as_float(__builtin_amdgcn_ds_bpermute(byte_addr, __float_as_int(v)));
}
template <int CTRL>
__device__ __forceinline__ float dpp_f(float v) {
    return __int_as_float(__builtin_amdgcn_update_dpp(
        0, __float_as_int(v), CTRL, 0xF, 0xF, true));
}
// xor-exchange across lanes; M constant after unroll -> branches fold.
__device__ __forceinline__ float xor_lane(float v, int M,
                                          int a4, int a16, int a32) {
    switch (M) {
    case 1:  return dpp_f<0xB1>(v);          // quad_perm [1,0,3,2]
    case 2:  return dpp_f<0x4E>(v);          // quad_perm [2,3,0,1]
    case 8:  return dpp_f<0x128>(v);         // row_ror:8 == lane^8
    case 4:  return bperm_f(a4,  v);
    case 16: return bperm_f(a16, v);
    default: return bperm_f(a32, v);         // 32
    }
}

__global__ __launch_bounds__(256, 4) void qsim_kernel(
    const float* __restrict__ x,       // (B, 10)
    const float* __restrict__ isc,     // (5, 20)
    const float* __restrict__ w,       // (5, 20)
    const float* __restrict__ oscale,  // (4)
    float* __restrict__ out,           // (B, 4)
    int B)
{
    const int lane = threadIdx.x & 63;
    const int wid  = (blockIdx.x * blockDim.x + threadIdx.x) >> 6;
    if (wid >= B) return;

    // ---- lane-parallel gate-coefficient computation (gates 0..49) ----
    float cUR, cUI, cVR, cVI;
    {
        const int g   = (lane < 50) ? lane : 49;
        const int q   = g % 10;
        const int lyr = g / 10;
        const float xq    = x[wid * OBS + q];
        const float alpha = isc[lyr * 2 * NQ + q]      * xq;
        const float beta  = isc[lyr * 2 * NQ + NQ + q] * xq;
        const float gamma = w[lyr * 2 * NQ + q];
        const float delta = w[lyr * 2 * NQ + NQ + q];
        float sa, ca, sp, cp, sd, cd;
        __sincosf(0.5f * alpha,          &sa, &ca);
        __sincosf(0.5f * (beta + gamma), &sp, &cp);
        __sincosf(0.5f * delta,          &sd, &cd);
        const float A = cd * ca, Bt = sd * sa;
        const float C = cd * sa, D  = sd * ca;
        cUR = (A - Bt) * cp;
        cUI = -(A + Bt) * sp;
        cVR = (C + D) * cp;
        cVI = (C - D) * sp;
    }

    // hoisted bpermute byte-addresses (loop-invariant)
    const int a4  = (lane ^ 4)  * 4;
    const int a16 = (lane ^ 16) * 4;
    const int a32 = (lane ^ 32) * 4;
    const int cnot_src  = (lane ^ (lane >> 1));
    const int addr_even = cnot_src * 4;            // r bit0 == 0
    const int addr_odd  = (cnot_src ^ 32) * 4;     // r bit0 == 1 (CNOT(3,4))

    f2 c[16];
#pragma unroll
    for (int r = 0; r < 16; ++r) c[r] = (f2){0.f, 0.f};
    c[0].x = (lane == 0) ? 1.f : 0.f;   // |0...0>

#define SWAPR(i, j) { f2 _t = c[i]; c[i] = c[j]; c[j] = _t; }

    for (int layer = 0; layer < NL; ++layer) {
        const int base = layer * NQ;   // wave-uniform

        // ---- fused single-qubit unitaries, one per qubit ----
#pragma unroll
        for (int q = 0; q < NQ; ++q) {
            const float ur = readlane_f(cUR, base + q);
            const float ui = readlane_f(cUI, base + q);
            const float vr = readlane_f(cVR, base + q);
            const float vi = readlane_f(cVI, base + q);

            if (q < 4) {
                // register-bit qubit: pair stride m inside the lane.
                const f2 kUU  = {ur, ur};
                const f2 kUIm = {-ui, ui};
                const f2 kVVn = {-vr, -vr};
                const f2 kVV  = {vr, vr};
                const f2 kVIm = {-vi, vi};
                const f2 kUIp = {ui, -ui};
                const int m = 1 << (3 - q);
#pragma unroll
                for (int r0 = 0; r0 < 16; ++r0) {
                    if (r0 & m) continue;
                    const int r1 = r0 | m;
                    const f2 c0 = c[r0], c1 = c[r1];
                    const f2 c0s = c0.yx, c1s = c1.yx;
                    c[r0] = kUU*c0 + kUIm*c0s + kVVn*c1 + kVIm*c1s;
                    c[r1] = kVV*c0 + kVIm*c0s + kUU*c1  + kUIp*c1s;
                }
            } else {
                // lane-bit qubit: butterfly exchange with lane^M.
                const int  M   = 1 << (9 - q);
                const bool bit = (lane & M) != 0;
                const float Pi = bit ? -ui : ui;
                const float Qr = bit ?  vr : -vr;
                const f2 kUU = {ur, ur};
                const f2 kPI = {-Pi, Pi};
                const f2 kQR = {Qr, Qr};
                const f2 kVI = {-vi, vi};
#pragma unroll
                for (int r = 0; r < 16; ++r) {
                    const f2 mv = c[r];
                    f2 pv;
                    pv.x = xor_lane(mv.x, M, a4, a16, a32);
                    pv.y = xor_lane(mv.y, M, a4, a16, a32);
                    c[r] = kUU*mv + kPI*mv.yx + kQR*pv + kVI*pv.yx;
                }
            }
        }

        // ---- CNOT ring: (0,1),(1,2),...,(8,9),(9,0), sequential ----
        // CNOT(0,1): ctrl r-bit3, tgt r-bit2 -> register swap
        SWAPR(8, 12) SWAPR(9, 13) SWAPR(10, 14) SWAPR(11, 15)
        // CNOT(1,2): ctrl r-bit2, tgt r-bit1
        SWAPR(4, 6)  SWAPR(5, 7)  SWAPR(12, 14) SWAPR(13, 15)
        // CNOT(2,3): ctrl r-bit1, tgt r-bit0
        SWAPR(2, 3)  SWAPR(6, 7)  SWAPR(10, 11) SWAPR(14, 15)
        // CNOT(3,4)..(8,9) fused: one bpermute per 32-bit value.
#pragma unroll
        for (int r = 0; r < 16; ++r) {
            const int addr = (r & 1) ? addr_odd : addr_even;
            c[r].x = bperm_f(addr, c[r].x);
            c[r].y = bperm_f(addr, c[r].y);
        }
        // CNOT(9,0): ctrl lane-bit0, tgt r-bit3 -> conditional register swap
        {
            const bool ctl = (lane & 1) != 0;
#pragma unroll
            for (int r = 0; r < 8; ++r) {
                const f2 t0 = c[r], t1 = c[r + 8];
                c[r]     = ctl ? t1 : t0;
                c[r + 8] = ctl ? t0 : t1;
            }
        }
    }

    // ---- <Z_i> for qubits 0..3 (all register bits) ----
    float z0 = 0.f, z1 = 0.f, z2 = 0.f, z3 = 0.f;
#pragma unroll
    for (int r = 0; r < 16; ++r) {
        const float pv = c[r].x * c[r].x + c[r].y * c[r].y;
        z0 += (r & 8) ? -pv : pv;
        z1 += (r & 4) ? -pv : pv;
        z2 += (r & 2) ? -pv : pv;
        z3 += (r & 1) ? -pv : pv;
    }
#pragma unroll
    for (int m = 1; m < 64; m <<= 1) {
        z0 += xor_lane(z0, m, a4, a16, a32);
        z1 += xor_lane(z1, m, a4, a16, a32);
        z2 += xor_lane(z2, m, a4, a16, a32);
        z3 += xor_lane(z3, m, a4, a16, a32);
    }
    if (lane == 0) {
        out[wid * 4 + 0] = z0 * oscale[0];
        out[wid * 4 + 1] = z1 * oscale[1];
        out[wid * 4 + 2] = z2 * oscale[2];
        out[wid * 4 + 3] = z3 * oscale[3];
    }
#undef SWAPR
}

extern "C" void kernel_launch(void* const* d_in, const int* in_sizes, int n_in,
                              void* d_out, int out_size, void* d_ws, size_t ws_size,
                              hipStream_t stream) {
    const float* x      = (const float*)d_in[0];
    const float* isc    = (const float*)d_in[1];
    const float* w      = (const float*)d_in[2];
    const float* oscale = (const float*)d_in[3];
    float* out = (float*)d_out;

    const int B = in_sizes[0] / OBS;             // 4096
    const int threads = 256;                     // 4 waves -> 4 samples per block
    const int blocks = (B * 64 + threads - 1) / threads;
    qsim_kernel<<<blocks, threads, 0, stream>>>(x, isc, w, oscale, out, B);
}